// Round 10
// baseline (16302.409 us; speedup 1.0000x reference)
//
#include <hip/hip_runtime.h>

#define NB 256
#define NT 1024

// problem dims
#define BB   64
#define TTS  2048
#define DKV  128
#define EEM  256
#define HH1  512
#define VVV  30
#define LLS  256
#define SOS_ID 1
#define SCALE_F 0.088388347648318447f  // 1/sqrt(128)

// ws float offsets
#define OFF_PM    0        // 256   slice partial max   [b*4+s]
#define OFF_PS    256      // 256   slice partial sum   [b*4+s]
#define OFF_PCTX  512      // 32768 slice partial ctx   [d*256 + b*4 + s]
#define OFF_WSE   33280    // 2048  energies for b=0
#define OFF_EMBT  35328    // 2*16384 embT double buffer [k*64+b]
#define OFF_H1    68096    // 2*32768 h1 double buffer   [k*64+b]
#define OFF_C1    133632   // 32768 c1                   [h*64+b]
#define OFF_H2R   166400   // 2*8192 h2 row-major        [b*128+d]
#define OFF_H2T   182784   // 2*8192 h2 [d*64+b]
#define OFF_C2    199168   // 8192  c2 [d*64+b]
#define OFF_BAR   207360   // barrier block: 4096 uints (region has 5632 slots)
#define OFF_KBF   212992   // bf16 K, 16777216 ushorts (8388608 float slots)
#define OFF_VBF   8601600  // bf16 V, 16777216 ushorts
#define WS_NEED_BYTES 67960832ull
#define PRED_SZ   491520   // 64*256*30

typedef unsigned u32x4 __attribute__((ext_vector_type(4)));

struct Params {
  const float* key; const float* value;
  const int* enc_len; const int* y;
  const float* emb;
  const float* Wih1; const float* Whh1; const float* bih1; const float* bhh1;
  const float* Wih2; const float* Whh2; const float* bih2; const float* bhh2;
  const float* obias;
  float* out; float* ws;
};

struct SMEM {
  union {
    struct {
      float ctxT[8192];                      // [d*64 + b], 32 KB
      union { float wt[8192]; float red[8192]; } u;  // weights (from regs) / reduction
    } a;
    struct { float wm[16]; float wS[16]; float wctx[2048]; float qh2[128]; } c;
  };
};

__device__ __forceinline__ float sigm(float x) { return 1.f / (1.f + __expf(-x)); }
__device__ __forceinline__ float tanh_f(float x) {
  float t = __expf(-2.f * fabsf(x));
  float r = (1.f - t) / (1.f + t);
  return x < 0.f ? -r : r;
}
__device__ __forceinline__ unsigned bfr(float f) {  // fp32 -> bf16 bits, RNE
  unsigned u = __float_as_uint(f);
  return (u + 0x7FFFu + ((u >> 16) & 1u)) >> 16;
}
// unpack a packed pair of bf16 (low / high 16 bits of a u32)
__device__ __forceinline__ float blo(unsigned u) { return __uint_as_float(u << 16); }
__device__ __forceinline__ float bhi(unsigned u) { return __uint_as_float(u & 0xffff0000u); }

// FULL grid barrier (fences: release writeback + acquire invalidate). Used
// only at C->A (and after setup): ONE L2 invalidate per step.
// layout (uints): [0,1024) arrival lines (group g at g*32); [1024] master cnt;
//                 [2048,3072) broadcast lines (group g at 2048+g*32).
__device__ __forceinline__ void gbar(unsigned* base, unsigned expect) {
  __syncthreads();
  if (threadIdx.x == 0) {
    __builtin_amdgcn_fence(__ATOMIC_RELEASE, "agent");
    const int grp = blockIdx.x >> 3;
    unsigned* gcnt = base + grp * 32;
    if (__hip_atomic_fetch_add(gcnt, 1u, __ATOMIC_RELAXED, __HIP_MEMORY_SCOPE_AGENT) == 7u) {
      unsigned* mcnt = base + 1024;
      if (__hip_atomic_fetch_add(mcnt, 1u, __ATOMIC_RELAXED, __HIP_MEMORY_SCOPE_AGENT) == 31u) {
        __hip_atomic_store(mcnt, 0u, __ATOMIC_RELAXED, __HIP_MEMORY_SCOPE_AGENT);
        #pragma unroll
        for (int gg = 0; gg < 32; ++gg)
          __hip_atomic_store(base + gg * 32, 0u, __ATOMIC_RELAXED, __HIP_MEMORY_SCOPE_AGENT);
        __builtin_amdgcn_fence(__ATOMIC_RELEASE, "agent");   // resets before bcast
        #pragma unroll
        for (int gg = 0; gg < 32; ++gg)
          __hip_atomic_store(base + 2048 + gg * 32, expect, __ATOMIC_RELAXED, __HIP_MEMORY_SCOPE_AGENT);
      }
    }
    unsigned* mygen = base + 2048 + grp * 32;
    int guard = 0;
    while ((int)(__hip_atomic_load(mygen, __ATOMIC_RELAXED, __HIP_MEMORY_SCOPE_AGENT) - expect) < 0) {
      __builtin_amdgcn_s_sleep(8);
      if (++guard > 10000000) break;
    }
    __builtin_amdgcn_fence(__ATOMIC_ACQUIRE, "agent");
  }
  __syncthreads();
}

// LIGHT grid barrier (no fences). Used on the fp32 fallback path only.
__device__ __forceinline__ void gbar_light(unsigned* base, unsigned expect) {
  asm volatile("s_waitcnt vmcnt(0) lgkmcnt(0)" ::: "memory");
  __syncthreads();
  if (threadIdx.x == 0) {
    const int grp = blockIdx.x >> 3;
    unsigned* gcnt = base + grp * 32;
    if (__hip_atomic_fetch_add(gcnt, 1u, __ATOMIC_RELAXED, __HIP_MEMORY_SCOPE_AGENT) == 7u) {
      unsigned* mcnt = base + 1024;
      if (__hip_atomic_fetch_add(mcnt, 1u, __ATOMIC_RELAXED, __HIP_MEMORY_SCOPE_AGENT) == 31u) {
        __hip_atomic_store(mcnt, 0u, __ATOMIC_RELAXED, __HIP_MEMORY_SCOPE_AGENT);
        #pragma unroll
        for (int gg = 0; gg < 32; ++gg)
          __hip_atomic_store(base + gg * 32, 0u, __ATOMIC_RELAXED, __HIP_MEMORY_SCOPE_AGENT);
        asm volatile("s_waitcnt vmcnt(0)" ::: "memory");
        #pragma unroll
        for (int gg = 0; gg < 32; ++gg)
          __hip_atomic_store(base + 2048 + gg * 32, expect, __ATOMIC_RELAXED, __HIP_MEMORY_SCOPE_AGENT);
      }
    }
    unsigned* mygen = base + 2048 + grp * 32;
    int guard = 0;
    while ((int)(__hip_atomic_load(mygen, __ATOMIC_RELAXED, __HIP_MEMORY_SCOPE_AGENT) - expect) < 0) {
      __builtin_amdgcn_s_sleep(8);
      if (++guard > 10000000) break;
    }
  }
  __syncthreads();
}

// LIGHT grid barrier WITH overlapped K/V prefetch (BF16 path).
// Order: drain stores -> issue touch loads (fire) -> RAW s_barrier (no
// compiler drain) -> arrival/poll -> RAW s_barrier -> vmcnt(0)+sink.
// The loads fly during the barrier wait; the post-barrier vmcnt is ~free.
// The sink keeps dest VGPRs alive until the loads retire (clobber hazard).
// Raw-barrier LDS safety: each wave drains lgkmcnt before arrival, and the
// LDS regions used on the two sides of each light barrier don't alias.
template<int J0, int J1>
__device__ __forceinline__ void gbar_light_pf(unsigned* base, unsigned expect,
                                              const unsigned short* kbf,
                                              const unsigned short* vbf,
                                              int b, int s, int len, int tid) {
  asm volatile("s_waitcnt vmcnt(0) lgkmcnt(0)" ::: "memory");
  constexpr int NP = J1 - J0;
  unsigned pk[NP], pv[NP];
  {
    const int lane = tid & 63, w = tid >> 6;
    const int sub = lane & 15, grp = lane >> 4;
    const int q = 4*w + s;
    const int r0 = q*4 + grp;
    const unsigned baseo = (unsigned)(b*TTS*DKV + sub*8) * 2u;
    #pragma unroll
    for (int j = 0; j < NP; ++j) {
      int t = r0 + 256*(J0 + j);
      int tc = t < len ? t : len - 1;     // clamp: harmless hot-line touches
      unsigned off = baseo + (unsigned)tc * (DKV*2);
      asm volatile("global_load_dword %0, %1, %2" : "=v"(pk[j]) : "v"(off), "s"(kbf));
      asm volatile("global_load_dword %0, %1, %2" : "=v"(pv[j]) : "v"(off), "s"(vbf));
    }
  }
  __builtin_amdgcn_s_barrier();
  if (threadIdx.x == 0) {
    const int grp2 = blockIdx.x >> 3;
    unsigned* gcnt = base + grp2 * 32;
    if (__hip_atomic_fetch_add(gcnt, 1u, __ATOMIC_RELAXED, __HIP_MEMORY_SCOPE_AGENT) == 7u) {
      unsigned* mcnt = base + 1024;
      if (__hip_atomic_fetch_add(mcnt, 1u, __ATOMIC_RELAXED, __HIP_MEMORY_SCOPE_AGENT) == 31u) {
        __hip_atomic_store(mcnt, 0u, __ATOMIC_RELAXED, __HIP_MEMORY_SCOPE_AGENT);
        #pragma unroll
        for (int gg = 0; gg < 32; ++gg)
          __hip_atomic_store(base + gg * 32, 0u, __ATOMIC_RELAXED, __HIP_MEMORY_SCOPE_AGENT);
        asm volatile("s_waitcnt vmcnt(0)" ::: "memory");   // resets before bcast
        #pragma unroll
        for (int gg = 0; gg < 32; ++gg)
          __hip_atomic_store(base + 2048 + gg * 32, expect, __ATOMIC_RELAXED, __HIP_MEMORY_SCOPE_AGENT);
      }
    }
    unsigned* mygen = base + 2048 + grp2 * 32;
    int guard = 0;
    while ((int)(__hip_atomic_load(mygen, __ATOMIC_RELAXED, __HIP_MEMORY_SCOPE_AGENT) - expect) < 0) {
      __builtin_amdgcn_s_sleep(8);
      if (++guard > 10000000) break;
    }
  }
  __builtin_amdgcn_s_barrier();
  // retire prefetch loads before their dest regs die (clobber hazard);
  // by now they've had the whole barrier to land -> near-free wait.
  asm volatile("s_waitcnt vmcnt(0)" ::: "memory");
  #pragma unroll
  for (int j = 0; j < NP; ++j)
    asm volatile("" :: "v"(pk[j]), "v"(pv[j]));
}

__device__ __forceinline__ void mac8x4(float acc[8][4], const float* wt, int k, float4 x4) {
  float4 wa = *(const float4*)(wt + k*8);
  float4 wb = *(const float4*)(wt + k*8 + 4);
  float wr[8] = {wa.x, wa.y, wa.z, wa.w, wb.x, wb.y, wb.z, wb.w};
  float xr[4] = {x4.x, x4.y, x4.z, x4.w};
  #pragma unroll
  for (int r = 0; r < 8; ++r)
    #pragma unroll
    for (int c = 0; c < 4; ++c)
      acc[r][c] += wr[r] * xr[c];
}

// cross-kslot reduce then per-wave partial to LDS
__device__ __forceinline__ void gate_reduce_store(float acc[8][4], float* red, int tid) {
  #pragma unroll
  for (int r = 0; r < 8; ++r) {
    #pragma unroll
    for (int c = 0; c < 4; ++c) {
      float v = acc[r][c];
      v += __shfl_xor(v, 16);
      v += __shfl_xor(v, 32);
      acc[r][c] = v;
    }
  }
  int wv = tid >> 6, b0 = tid & 15;
  if ((tid & 63) < 16) {
    #pragma unroll
    for (int r = 0; r < 8; ++r)
      *(float4*)(red + wv*512 + r*64 + b0*4) =
        make_float4(acc[r][0], acc[r][1], acc[r][2], acc[r][3]);
  }
}

// shared partial-merge tail: block's 16 waves -> one slice partial at bj
__device__ __forceinline__ void attn_merge_tail(float m, float S, float ca[8],
                                                float* pm, float* pS, float* pctx,
                                                SMEM* sm, int bj, int tid) {
  const int lane = tid & 63, w = tid >> 6;
  const int sub = lane & 15, grp = lane >> 4;
  #pragma unroll
  for (int off = 16; off <= 32; off <<= 1) {
    float mo = __shfl_xor(m, off);
    float So = __shfl_xor(S, off);
    float M2 = fmaxf(m, mo);
    float a0 = __expf(m - M2), a1 = __expf(mo - M2);
    S = S*a0 + So*a1;
    #pragma unroll
    for (int d = 0; d < 8; ++d)
      ca[d] = ca[d]*a0 + __shfl_xor(ca[d], off)*a1;
    m = M2;
  }
  if (lane == 0) { sm->c.wm[w] = m; sm->c.wS[w] = S; }
  if (grp == 0) {
    *(float4*)(sm->c.wctx + w*DKV + sub*8)     = make_float4(ca[0],ca[1],ca[2],ca[3]);
    *(float4*)(sm->c.wctx + w*DKV + sub*8 + 4) = make_float4(ca[4],ca[5],ca[6],ca[7]);
  }
  __syncthreads();
  if (tid < DKV) {
    int d = tid;
    float M = -1e30f;
    #pragma unroll
    for (int ww = 0; ww < 16; ++ww) M = fmaxf(M, sm->c.wm[ww]);
    float Z = 0.f, acc2 = 0.f;
    #pragma unroll
    for (int ww = 0; ww < 16; ++ww) {
      float aw = __expf(sm->c.wm[ww] - M);
      Z += aw * sm->c.wS[ww];
      acc2 += aw * sm->c.wctx[ww*DKV + d];
    }
    pctx[d*256 + bj] = acc2;
    if (d == 0) { pm[bj] = M; pS[bj] = Z; }
  }
}

// setup: initial context = mean over ALL T rows of V (fp32 source, runs once)
__device__ void attn_mean(const Params& p, float* pm, float* pS, float* pctx,
                          SMEM* sm, int bj, int tid) {
  const int lane = tid & 63, w = tid >> 6;
  const int b = bj >> 2, s = bj & 3;
  const int sub = lane & 15, grp = lane >> 4;
  const int q = 4*w + s;
  const int r0 = q*4 + grp;
  float S = 0.f;
  float ca[8] = {0.f,0.f,0.f,0.f,0.f,0.f,0.f,0.f};
  const float* vb = p.value + (size_t)b * TTS * DKV;
  #pragma unroll
  for (int j = 0; j < 8; ++j) {
    int t = r0 + 256*j;
    const float* vp = vb + (size_t)t * DKV + sub*8;
    float4 va = *(const float4*)vp;
    float4 vb4 = *(const float4*)(vp + 4);
    S += 1.f;
    ca[0]+=va.x;  ca[1]+=va.y;  ca[2]+=va.z;  ca[3]+=va.w;
    ca[4]+=vb4.x; ca[5]+=vb4.y; ca[6]+=vb4.z; ca[7]+=vb4.w;
  }
  attn_merge_tail(0.f, S, ca, pm, pS, pctx, sm, b*4 + s, tid);
}

// Phase C: attention partials, R2 mapping (slot q=4w+s, rows 4q+grp+256j),
// guarded chunk loads (lowest-FETCH form). Query row staged via coherent
// sc-loads into LDS (h2r crosses only a light barrier; its lines are
// partial-written per block so default-cached reads would see stale bytes).
template<bool BF16>
__device__ void phase_attn_main(const Params& p, const float* qrow,
                                const unsigned short* kbf, const unsigned short* vbf,
                                float* pm, float* pS, float* pctx, float* wsE,
                                SMEM* sm, int bj, int tid) {
  const int lane = tid & 63, w = tid >> 6;
  const int b = bj >> 2, s = bj & 3;
  const int len = p.enc_len[b];
  const int sub = lane & 15, grp = lane >> 4;
  const int q = 4*w + s;
  const int r0 = q*4 + grp;
  float m = -1e30f, S = 0.f;
  float ca[8] = {0.f,0.f,0.f,0.f,0.f,0.f,0.f,0.f};
  if constexpr (BF16) {
    if (tid < 32) {
      u32x4 qv;
      asm volatile("global_load_dwordx4 %0, %1, %2 sc0 sc1"
                   : "=v"(qv) : "v"((unsigned)(tid*16)), "s"(qrow + b*DKV));
      asm volatile("s_waitcnt vmcnt(0)" ::: "memory");
      *(u32x4*)&sm->c.qh2[tid*4] = qv;
    }
    __syncthreads();
  }
  int NJ = 0;
  { int d = len - 4*q; if (d > 0) { NJ = (d + 255) >> 8; if (NJ > 8) NJ = 8; } }
  if (NJ > 0) {
    float q8[8];
    if constexpr (BF16) {
      const float* qp = sm->c.qh2 + sub*8;
      float4 qa = *(const float4*)qp;
      float4 qb = *(const float4*)(qp + 4);
      q8[0]=qa.x; q8[1]=qa.y; q8[2]=qa.z; q8[3]=qa.w;
      q8[4]=qb.x; q8[5]=qb.y; q8[6]=qb.z; q8[7]=qb.w;
    } else {
      const float* qp = qrow + b*DKV + sub*8;
      float4 qa = *(const float4*)qp;
      float4 qb = *(const float4*)(qp + 4);
      q8[0]=qa.x; q8[1]=qa.y; q8[2]=qa.z; q8[3]=qa.w;
      q8[4]=qb.x; q8[5]=qb.y; q8[6]=qb.z; q8[7]=qb.w;
    }
    float e[8];
    #pragma unroll
    for (int j = 0; j < 8; ++j) e[j] = -1e30f;
    if constexpr (BF16) {
      const unsigned short* kb  = kbf + (size_t)(b*TTS)*DKV + sub*8;
      const unsigned short* vbp = vbf + (size_t)(b*TTS)*DKV + sub*8;
      uint4 kq[8], vq[8];
      #pragma unroll
      for (int j = 0; j < 8; ++j) {
        if (j < NJ) {
          int t = r0 + 256*j;
          int tc = t < len ? t : len - 1;
          kq[j] = *(const uint4*)(kb  + (size_t)tc * DKV);
          vq[j] = *(const uint4*)(vbp + (size_t)tc * DKV);
        }
      }
      #pragma unroll
      for (int j = 0; j < 8; ++j) {
        if (j < NJ) {
          float ep = blo(kq[j].x)*q8[0] + bhi(kq[j].x)*q8[1]
                   + blo(kq[j].y)*q8[2] + bhi(kq[j].y)*q8[3]
                   + blo(kq[j].z)*q8[4] + bhi(kq[j].z)*q8[5]
                   + blo(kq[j].w)*q8[6] + bhi(kq[j].w)*q8[7];
          ep += __shfl_xor(ep, 1); ep += __shfl_xor(ep, 2);
          ep += __shfl_xor(ep, 4); ep += __shfl_xor(ep, 8);
          int t = r0 + 256*j;
          e[j] = (t < len) ? ep * SCALE_F : -1e30f;
          if (b == 0 && sub == 0 && t < len) wsE[t] = e[j];
        }
      }
      m = fmaxf(fmaxf(fmaxf(e[0],e[1]), fmaxf(e[2],e[3])),
                fmaxf(fmaxf(e[4],e[5]), fmaxf(e[6],e[7])));
      float pr[8];
      #pragma unroll
      for (int j = 0; j < 8; ++j) {
        pr[j] = (e[j] > -1e29f) ? __expf(e[j] - m) : 0.f;
        S += pr[j];
      }
      #pragma unroll
      for (int j = 0; j < 8; ++j) {
        if (j < NJ) {
          ca[0] += pr[j]*blo(vq[j].x); ca[1] += pr[j]*bhi(vq[j].x);
          ca[2] += pr[j]*blo(vq[j].y); ca[3] += pr[j]*bhi(vq[j].y);
          ca[4] += pr[j]*blo(vq[j].z); ca[5] += pr[j]*bhi(vq[j].z);
          ca[6] += pr[j]*blo(vq[j].w); ca[7] += pr[j]*bhi(vq[j].w);
        }
      }
    } else {
      // fp32 fallback (small-ws path)
      for (int j = 0; j < NJ; ++j) {
        int t = r0 + 256*j;
        int tc = t < len ? t : len - 1;
        const float* kp = p.key + (size_t)(b*TTS + tc)*DKV + sub*8;
        float4 ka = *(const float4*)kp;
        float4 kb2 = *(const float4*)(kp + 4);
        float ep = ka.x*q8[0] + ka.y*q8[1] + ka.z*q8[2] + ka.w*q8[3]
                 + kb2.x*q8[4] + kb2.y*q8[5] + kb2.z*q8[6] + kb2.w*q8[7];
        ep += __shfl_xor(ep, 1); ep += __shfl_xor(ep, 2);
        ep += __shfl_xor(ep, 4); ep += __shfl_xor(ep, 8);
        e[j] = (t < len) ? ep * SCALE_F : -1e30f;
        if (b == 0 && sub == 0 && t < len) wsE[t] = e[j];
      }
      m = e[0];
      #pragma unroll
      for (int j = 1; j < 8; ++j) m = fmaxf(m, e[j]);
      float pr[8];
      #pragma unroll
      for (int j = 0; j < 8; ++j) {
        pr[j] = (e[j] > -1e29f) ? __expf(e[j] - m) : 0.f;
        S += pr[j];
      }
      for (int j = 0; j < NJ; ++j) {
        int t = r0 + 256*j;
        int tc = t < len ? t : len - 1;
        const float* vp = p.value + (size_t)(b*TTS + tc)*DKV + sub*8;
        float4 va = *(const float4*)vp;
        float4 vb4 = *(const float4*)(vp + 4);
        ca[0] += pr[j]*va.x;  ca[1] += pr[j]*va.y;
        ca[2] += pr[j]*va.z;  ca[3] += pr[j]*va.w;
        ca[4] += pr[j]*vb4.x; ca[5] += pr[j]*vb4.y;
        ca[6] += pr[j]*vb4.z; ca[7] += pr[j]*vb4.w;
      }
    }
  }
  attn_merge_tail(m, S, ca, pm, pS, pctx, sm, bj, tid);
}

template<bool BF16>
__global__ void
__attribute__((amdgpu_flat_work_group_size(NT, NT), amdgpu_waves_per_eu(4, 4)))
decoder_kernel(Params p) {
  const int tid = threadIdx.x;
  const int bj = blockIdx.x;
  float* ws = p.ws;
  unsigned* bar = (unsigned*)(ws + OFF_BAR);
  float* pm = ws + OFF_PM;
  float* pS = ws + OFF_PS;
  float* pctx = ws + OFF_PCTX;
  float* wsE = ws + OFF_WSE;
  float* embT0 = ws + OFF_EMBT;
  float* embT1 = ws + OFF_EMBT + EEM*BB;
  float* h1b0 = ws + OFF_H1;
  float* h1b1 = ws + OFF_H1 + HH1*BB;
  float* c1 = ws + OFF_C1;
  float* h2r0 = ws + OFF_H2R;
  float* h2r1 = ws + OFF_H2R + BB*DKV;
  float* h2t0 = ws + OFF_H2T;
  float* h2t1 = ws + OFF_H2T + DKV*BB;
  float* c2 = ws + OFF_C2;
  unsigned short* kbf = (unsigned short*)(ws + OFF_KBF);
  unsigned short* vbf = (unsigned short*)(ws + OFF_VBF);
  unsigned genc = 0;   // local barrier generation

  const int b_my = bj >> 2, s_my = bj & 3;
  const int len_my = p.enc_len[b_my];

  __shared__ SMEM sm;

  // -------- persistent register state: step-invariant weights & biases --------
  float wr1[8] = {0,0,0,0,0,0,0,0};
  if (tid < 896) {
    #pragma unroll
    for (int r = 0; r < 8; ++r) {
      int grow = (r >> 1)*HH1 + 2*bj + (r & 1);
      wr1[r] = (tid < 384) ? p.Wih1[(size_t)grow*384 + tid]
                           : p.Whh1[(size_t)grow*HH1 + (tid - 384)];
    }
  }
  float wr2[8] = {0,0,0,0,0,0,0,0};
  if (bj < 64 && tid < 640) {
    #pragma unroll
    for (int r = 0; r < 8; ++r) {
      int grow = (r >> 1)*DKV + 2*bj + (r & 1);
      wr2[r] = (tid < 512) ? p.Wih2[(size_t)grow*HH1 + tid]
                           : p.Whh2[(size_t)grow*DKV + (tid - 512)];
    }
  }
  float bsum1 = 0.f, bsum2 = 0.f;
  if (tid < 512) {
    int r = tid >> 6;
    int g1 = (r >> 1)*HH1 + 2*bj + (r & 1);
    bsum1 = p.bih1[g1] + p.bhh1[g1];
    if (bj < 64) {
      int g2 = (r >> 1)*DKV + 2*bj + (r & 1);
      bsum2 = p.bih2[g2] + p.bhh2[g2];
    }
  }

  // ---------------- setup ----------------
  {
    int gid = bj*NT + tid;
    for (int idx = gid; idx < (OFF_BAR - OFF_H1); idx += NB*NT) ws[OFF_H1 + idx] = 0.f;
    for (int idx = gid; idx < EEM*BB; idx += NB*NT) {
      int k = idx >> 6, b = idx & 63;
      embT0[k*64 + b] = p.emb[SOS_ID*EEM + k];
    }
    if constexpr (BF16) {
      // convert K,V fp32 -> bf16 (RNE), 8 floats -> one uint4 store
      const int NG = (BB*TTS*DKV) / 8;   // 2097152 groups per tensor
      for (int g = gid; g < NG; g += NB*NT) {
        const float4* src = (const float4*)p.key + (size_t)g*2;
        float4 a = src[0], bq = src[1];
        uint4 o;
        o.x = bfr(a.x)  | (bfr(a.y)  << 16);
        o.y = bfr(a.z)  | (bfr(a.w)  << 16);
        o.z = bfr(bq.x) | (bfr(bq.y) << 16);
        o.w = bfr(bq.z) | (bfr(bq.w) << 16);
        ((uint4*)kbf)[g] = o;
      }
      for (int g = gid; g < NG; g += NB*NT) {
        const float4* src = (const float4*)p.value + (size_t)g*2;
        float4 a = src[0], bq = src[1];
        uint4 o;
        o.x = bfr(a.x)  | (bfr(a.y)  << 16);
        o.y = bfr(a.z)  | (bfr(a.w)  << 16);
        o.z = bfr(bq.x) | (bfr(bq.y) << 16);
        o.w = bfr(bq.z) | (bfr(bq.w) << 16);
        ((uint4*)vbf)[g] = o;
      }
    }
    attn_mean(p, pm, pS, pctx, &sm, bj, tid);
  }
  gbar(bar, ++genc);   // FULL: setup writes (K/V etc.) flushed + all L2s clean

  for (int i = 0; i <= LLS; ++i) {
    const int cur = i & 1;
    float* h1c = cur ? h1b1 : h1b0;
    const float* h1p = cur ? h1b0 : h1b1;
    float* h2rc = cur ? h2r1 : h2r0;
    const float* h2rp = cur ? h2r0 : h2r1;
    float* h2tc = cur ? h2t1 : h2t0;
    const float* h2tp = cur ? h2t0 : h2t1;
    const float* et = cur ? embT1 : embT0;
    float* etn = cur ? embT0 : embT1;

    // ================= phase A =================
    // A0: combine 4 slice partials -> ctx in LDS (transposed [d][b])
    {
      int b = tid & 63, dg = tid >> 6;
      float4 m4 = *(const float4*)(pm + b*4);
      float4 s4 = *(const float4*)(pS + b*4);
      float M = fmaxf(fmaxf(m4.x, m4.y), fmaxf(m4.z, m4.w));
      float a0 = __expf(m4.x - M), a1 = __expf(m4.y - M);
      float a2 = __expf(m4.z - M), a3 = __expf(m4.w - M);
      float Z = a0*s4.x + a1*s4.y + a2*s4.z + a3*s4.w;
      float iZ = 1.f / Z;
      a0 *= iZ; a1 *= iZ; a2 *= iZ; a3 *= iZ;
      #pragma unroll
      for (int jj = 0; jj < 8; ++jj) {
        int d = dg + jj*16;
        float4 c4 = *(const float4*)(pctx + d*256 + b*4);
        sm.a.ctxT[d*64 + b] = a0*c4.x + a1*c4.y + a2*c4.z + a3*c4.w;
      }
    }
    // A1 weights: registers -> LDS (step-invariant, no global traffic)
    if (i < LLS && tid < 896) {
      *(float4*)(sm.a.u.wt + tid*8)     = make_float4(wr1[0], wr1[1], wr1[2], wr1[3]);
      *(float4*)(sm.a.u.wt + tid*8 + 4) = make_float4(wr1[4], wr1[5], wr1[6], wr1[7]);
    }
    __syncthreads();

    if (i < LLS) {
      // A1: LSTM1 for h in {2*bj, 2*bj+1}; 8 gate rows per block
      {
        const int b0 = tid & 15, ks = tid >> 4;   // 16 b-quads x 64 k-slots
        float acc[8][4];
        #pragma unroll
        for (int r = 0; r < 8; ++r) { acc[r][0]=0.f; acc[r][1]=0.f; acc[r][2]=0.f; acc[r][3]=0.f; }
        #pragma unroll
        for (int j = 0; j < 4; ++j) {             // emb segment k<256
          int k = ks*4 + j;
          float4 x4 = *(const float4*)(et + k*64 + b0*4);
          mac8x4(acc, sm.a.u.wt, k, x4);
        }
        #pragma unroll
        for (int j = 0; j < 2; ++j) {             // ctx segment
          int d = ks*2 + j;
          float4 x4 = *(const float4*)(sm.a.ctxT + d*64 + b0*4);
          mac8x4(acc, sm.a.u.wt, 256 + d, x4);
        }
        #pragma unroll
        for (int j = 0; j < 8; ++j) {             // h1 segment
          int kk = ks*8 + j;
          float4 x4 = *(const float4*)(h1p + kk*64 + b0*4);
          mac8x4(acc, sm.a.u.wt, 384 + kk, x4);
        }
        __syncthreads();    // wt reads done; red aliases wt
        gate_reduce_store(acc, sm.a.u.red, tid);
      }
      __syncthreads();
      if (tid < 512) {
        int r = tid >> 6, b = tid & 63;
        float s = 0.f;
        #pragma unroll
        for (int w2 = 0; w2 < 16; ++w2) s += sm.a.u.red[w2*512 + r*64 + b];
        s += bsum1;
        sm.a.u.red[r*64 + b] = s;
      }
      __syncthreads();
      if (tid < 128) {
        int hh = tid >> 6, b = tid & 63;
        int h = 2*bj + hh;
        float gi = sm.a.u.red[(hh+0)*64 + b];
        float gf = sm.a.u.red[(hh+2)*64 + b];
        float gg = sm.a.u.red[(hh+4)*64 + b];
        float go = sm.a.u.red[(hh+6)*64 + b];
        float co = c1[h*64 + b];
        float cn = sigm(gf)*co + sigm(gi)*tanh_f(gg);
        float hn = sigm(go)*tanh_f(cn);
        c1[h*64 + b] = cn;                     // block-private: default store
        // h1 crosses only the light A->B barrier: write-through coherent store
        asm volatile("global_store_dword %0, %1, %2 sc0 sc1"
                     :: "v"((unsigned)((h*64 + b)*4)), "v"(hn), "s"(h1c) : "memory");
      }
    }

    if (i >= 1) {
      // A2: logits for step i-1
      if (tid >= 960) {
        int ln = tid - 960;
        int oi = bj*8 + (ln >> 3);
        int sub = ln & 7;
        if (oi < BB*VVV) {
          int b = oi / VVV, v = oi - b*VVV;
          float a = 0.f;
          if (sub < 4) {
            #pragma unroll 8
            for (int e0 = 0; e0 < 32; ++e0) {
              int e = sub*32 + e0;
              a += h2rp[b*DKV + e] * p.emb[v*EEM + e];
            }
          } else {
            #pragma unroll 8
            for (int e0 = 0; e0 < 32; ++e0) {
              int d = (sub - 4)*32 + e0;
              a += sm.a.ctxT[d*64 + b] * p.emb[v*EEM + 128 + d];
            }
          }
          a += __shfl_xor(a, 1); a += __shfl_xor(a, 2); a += __shfl_xor(a, 4);
          if (sub == 0) p.out[((size_t)b*LLS + (i-1))*VVV + v] = a + p.obias[v];
        }
      }
      // A3: attention plot row i-1
      if (tid >= 896 && tid < 904) {
        int t = bj*8 + (tid - 896);
        int len0 = p.enc_len[0];
        float v = 0.f;
        if (t < len0) {
          float m0 = pm[0], m1 = pm[1], m2 = pm[2], m3 = pm[3];
          float M = fmaxf(fmaxf(m0, m1), fmaxf(m2, m3));
          float Z = __expf(m0 - M)*pS[0] + __expf(m1 - M)*pS[1]
                  + __expf(m2 - M)*pS[2] + __expf(m3 - M)*pS[3];
          v = __expf(wsE[t] - M) / Z;
        }
        p.out[PRED_SZ + (size_t)(i-1)*TTS + t] = v;
      }
    }

    if (i == LLS) break;

    // light A->B barrier with overlapped prefetch of chunks 0..4
    if constexpr (BF16)
      gbar_light_pf<0,4>(bar, ++genc, kbf, vbf, b_my, s_my, len_my, tid);
    else
      gbar_light(bar, ++genc);

    // ================= phase B =================
    if (bj < 64) {
      if (tid < 640) {
        *(float4*)(sm.a.u.wt + tid*8)     = make_float4(wr2[0], wr2[1], wr2[2], wr2[3]);
        *(float4*)(sm.a.u.wt + tid*8 + 4) = make_float4(wr2[4], wr2[5], wr2[6], wr2[7]);
      }
      __syncthreads();
      {
        const int b0 = tid & 15, ks = tid >> 4;
        float acc[8][4];
        #pragma unroll
        for (int r = 0; r < 8; ++r) { acc[r][0]=0.f; acc[r][1]=0.f; acc[r][2]=0.f; acc[r][3]=0.f; }
        #pragma unroll
        for (int j = 0; j < 8; ++j) {            // h1 segment (512)
          int k = ks*8 + j;
          float4 x4 = *(const float4*)(h1c + k*64 + b0*4);
          mac8x4(acc, sm.a.u.wt, k, x4);
        }
        #pragma unroll
        for (int j = 0; j < 2; ++j) {            // h2 segment (128)
          int d = ks*2 + j;
          float4 x4 = *(const float4*)(h2tp + d*64 + b0*4);
          mac8x4(acc, sm.a.u.wt, 512 + d, x4);
        }
        __syncthreads();
        gate_reduce_store(acc, sm.a.u.red, tid);
      }
      __syncthreads();
      if (tid < 512) {
        int r = tid >> 6, b = tid & 63;
        float s = 0.f;
        #pragma unroll
        for (int w2 = 0; w2 < 16; ++w2) s += sm.a.u.red[w2*512 + r*64 + b];
        s += bsum2;
        sm.a.u.red[r*64 + b] = s;
      }
      __syncthreads();
      if (tid < 128) {
        int hh = tid >> 6, b = tid & 63;
        int d2 = 2*bj + hh;
        float gi = sm.a.u.red[(hh+0)*64 + b];
        float gf = sm.a.u.red[(hh+2)*64 + b];
        float gg = sm.a.u.red[(hh+4)*64 + b];
        float go = sm.a.u.red[(hh+6)*64 + b];
        float co = c2[d2*64 + b];
        float cn = sigm(gf)*co + sigm(gi)*tanh_f(gg);
        float hn = sigm(go)*tanh_f(cn);
        c2[d2*64 + b] = cn;                    // block-private: default
        h2tc[d2*64 + b] = hn;                  // read next step across FULL: default
        // h2r crosses only the light B->C barrier: coherent write-through
        asm volatile("global_store_dword %0, %1, %2 sc0 sc1"
                     :: "v"((unsigned)((b*DKV + d2)*4)), "v"(hn), "s"(h2rc) : "memory");
      }
    } else if (bj < 128) {
      // stage embeddings for step i+1 (read next step across the FULL barrier)
      int sn = i + 1;
      if (sn < LLS && tid < 256) {
        int idx = (bj - 64)*256 + tid;
        int k = idx >> 6, b = idx & 63;
        int id = p.y[b*LLS + sn - 1];
        etn[k*64 + b] = p.emb[(size_t)id*EEM + k];
      }
    }

    // light B->C barrier with overlapped prefetch of chunks 4..8
    if constexpr (BF16)
      gbar_light_pf<4,8>(bar, ++genc, kbf, vbf, b_my, s_my, len_my, tid);
    else
      gbar_light(bar, ++genc);

    // ================= phase C =================
    phase_attn_main<BF16>(p, h2rc, kbf, vbf, pm, pS, pctx, wsE, &sm, bj, tid);
    gbar(bar, ++genc);   // FULL: flush pctx/pm/pS/h2t/etn + one invalidate/step
  }
}

__global__ void init_bar_kernel(unsigned* bar) {
  int i = blockIdx.x * blockDim.x + threadIdx.x;
  if (i < 4096) bar[i] = 0u;
}

extern "C" void kernel_launch(void* const* d_in, const int* in_sizes, int n_in,
                              void* d_out, int out_size, void* d_ws, size_t ws_size,
                              hipStream_t stream) {
  Params prm;
  prm.key     = (const float*)d_in[0];
  prm.value   = (const float*)d_in[1];
  prm.enc_len = (const int*)d_in[2];
  prm.y       = (const int*)d_in[3];
  prm.emb     = (const float*)d_in[4];
  prm.Wih1    = (const float*)d_in[5];
  prm.Whh1    = (const float*)d_in[6];
  prm.bih1    = (const float*)d_in[7];
  prm.bhh1    = (const float*)d_in[8];
  prm.Wih2    = (const float*)d_in[9];
  prm.Whh2    = (const float*)d_in[10];
  prm.bih2    = (const float*)d_in[11];
  prm.bhh2    = (const float*)d_in[12];
  prm.obias   = (const float*)d_in[13];
  prm.out = (float*)d_out;
  prm.ws  = (float*)d_ws;

  unsigned* bar = (unsigned*)((float*)d_ws + OFF_BAR);
  init_bar_kernel<<<16, 256, 0, stream>>>(bar);

  void* args[] = { &prm };
  if (ws_size >= WS_NEED_BYTES) {
    hipError_t e = hipLaunchCooperativeKernel((const void*)decoder_kernel<true>,
                                              dim3(NB), dim3(NT), args, 0, stream);
    if (e != hipSuccess) decoder_kernel<true><<<dim3(NB), dim3(NT), 0, stream>>>(prm);
  } else {
    hipError_t e = hipLaunchCooperativeKernel((const void*)decoder_kernel<false>,
                                              dim3(NB), dim3(NT), args, 0, stream);
    if (e != hipSuccess) decoder_kernel<false><<<dim3(NB), dim3(NT), 0, stream>>>(prm);
  }
}

// Round 11
// 15382.391 us; speedup vs baseline: 1.0598x; 1.0598x over previous
//
#include <hip/hip_runtime.h>

#define NB 256
#define NT 1024

// problem dims
#define BB   64
#define TTS  2048
#define DKV  128
#define EEM  256
#define HH1  512
#define VVV  30
#define LLS  256
#define SOS_ID 1
#define SCALE_F 0.088388347648318447f  // 1/sqrt(128)

// ws float offsets
#define OFF_PM    0        // 256   slice partial max   [b*4+s]
#define OFF_PS    256      // 256   slice partial sum   [b*4+s]
#define OFF_PCTX  512      // 32768 slice partial ctx   [d*256 + b*4 + s]
#define OFF_WSE   33280    // 2048  energies for b=0
#define OFF_EMBT  35328    // 2*16384 embT double buffer [k*64+b]
#define OFF_H1    68096    // 2*32768 h1 double buffer   [k*64+b]
#define OFF_C1    133632   // 32768 c1                   [h*64+b]
#define OFF_H2R   166400   // 2*8192 h2 row-major        [b*128+d]
#define OFF_H2T   182784   // 2*8192 h2 [d*64+b]
#define OFF_C2    199168   // 8192  c2 [d*64+b]
#define OFF_BAR   207360   // barrier block: 4096 uints (region has 5632 slots)
#define OFF_KBF   212992   // bf16 K, 16777216 ushorts (8388608 float slots)
#define OFF_VBF   8601600  // bf16 V, 16777216 ushorts
#define WS_NEED_BYTES 67960832ull
#define PRED_SZ   491520   // 64*256*30

typedef unsigned u32x4 __attribute__((ext_vector_type(4)));

struct Params {
  const float* key; const float* value;
  const int* enc_len; const int* y;
  const float* emb;
  const float* Wih1; const float* Whh1; const float* bih1; const float* bhh1;
  const float* Wih2; const float* Whh2; const float* bih2; const float* bhh2;
  const float* obias;
  float* out; float* ws;
};

struct SMEM {
  union {
    struct {
      float ctxT[8192];                      // [d*64 + b], 32 KB
      union { float wt[8192]; float red[8192]; } u;  // weights (from regs) / reduction
    } a;
    struct { float wm[16]; float wS[16]; float wctx[2048]; float qh2[128]; } c;
  };
};

__device__ __forceinline__ float sigm(float x) { return 1.f / (1.f + __expf(-x)); }
__device__ __forceinline__ float tanh_f(float x) {
  float t = __expf(-2.f * fabsf(x));
  float r = (1.f - t) / (1.f + t);
  return x < 0.f ? -r : r;
}
__device__ __forceinline__ unsigned bfr(float f) {  // fp32 -> bf16 bits, RNE
  unsigned u = __float_as_uint(f);
  return (u + 0x7FFFu + ((u >> 16) & 1u)) >> 16;
}
// unpack a packed pair of bf16 (low / high 16 bits of a u32)
__device__ __forceinline__ float blo(unsigned u) { return __uint_as_float(u << 16); }
__device__ __forceinline__ float bhi(unsigned u) { return __uint_as_float(u & 0xffff0000u); }

// FULL grid barrier (fences: release writeback + acquire invalidate). Used
// only at C->A (and after setup): ONE L2 invalidate per step.
// layout (uints): [0,1024) arrival lines (group g at g*32); [1024] master cnt;
//                 [2048,3072) broadcast lines (group g at 2048+g*32).
__device__ __forceinline__ void gbar(unsigned* base, unsigned expect) {
  __syncthreads();
  if (threadIdx.x == 0) {
    __builtin_amdgcn_fence(__ATOMIC_RELEASE, "agent");
    const int grp = blockIdx.x >> 3;
    unsigned* gcnt = base + grp * 32;
    if (__hip_atomic_fetch_add(gcnt, 1u, __ATOMIC_RELAXED, __HIP_MEMORY_SCOPE_AGENT) == 7u) {
      unsigned* mcnt = base + 1024;
      if (__hip_atomic_fetch_add(mcnt, 1u, __ATOMIC_RELAXED, __HIP_MEMORY_SCOPE_AGENT) == 31u) {
        __hip_atomic_store(mcnt, 0u, __ATOMIC_RELAXED, __HIP_MEMORY_SCOPE_AGENT);
        #pragma unroll
        for (int gg = 0; gg < 32; ++gg)
          __hip_atomic_store(base + gg * 32, 0u, __ATOMIC_RELAXED, __HIP_MEMORY_SCOPE_AGENT);
        __builtin_amdgcn_fence(__ATOMIC_RELEASE, "agent");   // resets before bcast
        #pragma unroll
        for (int gg = 0; gg < 32; ++gg)
          __hip_atomic_store(base + 2048 + gg * 32, expect, __ATOMIC_RELAXED, __HIP_MEMORY_SCOPE_AGENT);
      }
    }
    unsigned* mygen = base + 2048 + grp * 32;
    int guard = 0;
    while ((int)(__hip_atomic_load(mygen, __ATOMIC_RELAXED, __HIP_MEMORY_SCOPE_AGENT) - expect) < 0) {
      __builtin_amdgcn_s_sleep(8);
      if (++guard > 10000000) break;
    }
    __builtin_amdgcn_fence(__ATOMIC_ACQUIRE, "agent");
  }
  __syncthreads();
}

// LIGHT grid barrier (no fences, no invalidate). Ordering: vmcnt(0) drains
// this block's stores (incl. sc write-through -> L3) before arrival.
__device__ __forceinline__ void gbar_light(unsigned* base, unsigned expect) {
  asm volatile("s_waitcnt vmcnt(0) lgkmcnt(0)" ::: "memory");
  __syncthreads();
  if (threadIdx.x == 0) {
    const int grp = blockIdx.x >> 3;
    unsigned* gcnt = base + grp * 32;
    if (__hip_atomic_fetch_add(gcnt, 1u, __ATOMIC_RELAXED, __HIP_MEMORY_SCOPE_AGENT) == 7u) {
      unsigned* mcnt = base + 1024;
      if (__hip_atomic_fetch_add(mcnt, 1u, __ATOMIC_RELAXED, __HIP_MEMORY_SCOPE_AGENT) == 31u) {
        __hip_atomic_store(mcnt, 0u, __ATOMIC_RELAXED, __HIP_MEMORY_SCOPE_AGENT);
        #pragma unroll
        for (int gg = 0; gg < 32; ++gg)
          __hip_atomic_store(base + gg * 32, 0u, __ATOMIC_RELAXED, __HIP_MEMORY_SCOPE_AGENT);
        asm volatile("s_waitcnt vmcnt(0)" ::: "memory");
        #pragma unroll
        for (int gg = 0; gg < 32; ++gg)
          __hip_atomic_store(base + 2048 + gg * 32, expect, __ATOMIC_RELAXED, __HIP_MEMORY_SCOPE_AGENT);
      }
    }
    unsigned* mygen = base + 2048 + grp * 32;
    int guard = 0;
    while ((int)(__hip_atomic_load(mygen, __ATOMIC_RELAXED, __HIP_MEMORY_SCOPE_AGENT) - expect) < 0) {
      __builtin_amdgcn_s_sleep(8);
      if (++guard > 10000000) break;
    }
  }
  __syncthreads();
}

// LIGHT grid barrier WITH overlapped K/V prefetch. Order: drain stores ->
// issue touch loads (fire) -> RAW s_barrier (no compiler drain) ->
// arrival/poll -> RAW s_barrier -> vmcnt(0)+sink. Loads fly during the wait.
// VOLUME DISCIPLINE (R10 lesson): per-XCD L2 = 4MB; 32 blocks/XCD x NP
// chunks x 32KB must stay <= ~3MB -> NP=3. Placed ONLY at B->C (no
// intervening phase to evict before use; R10's A->B prefetch double-fetched).
template<int J0, int J1>
__device__ __forceinline__ void gbar_light_pf(unsigned* base, unsigned expect,
                                              const unsigned short* kbf,
                                              const unsigned short* vbf,
                                              int b, int s, int len, int tid) {
  asm volatile("s_waitcnt vmcnt(0) lgkmcnt(0)" ::: "memory");
  constexpr int NP = J1 - J0;
  unsigned pk[NP], pv[NP];
  {
    const int lane = tid & 63, w = tid >> 6;
    const int sub = lane & 15, grp = lane >> 4;
    const int q = 4*w + s;
    const int r0 = q*4 + grp;
    const unsigned baseo = (unsigned)(b*TTS*DKV + sub*8) * 2u;
    #pragma unroll
    for (int j = 0; j < NP; ++j) {
      int t = r0 + 256*(J0 + j);
      int tc = t < len ? t : len - 1;     // clamp: harmless hot-line touches
      unsigned off = baseo + (unsigned)tc * (DKV*2);
      asm volatile("global_load_dword %0, %1, %2" : "=v"(pk[j]) : "v"(off), "s"(kbf));
      asm volatile("global_load_dword %0, %1, %2" : "=v"(pv[j]) : "v"(off), "s"(vbf));
    }
  }
  __builtin_amdgcn_s_barrier();
  if (threadIdx.x == 0) {
    const int grp2 = blockIdx.x >> 3;
    unsigned* gcnt = base + grp2 * 32;
    if (__hip_atomic_fetch_add(gcnt, 1u, __ATOMIC_RELAXED, __HIP_MEMORY_SCOPE_AGENT) == 7u) {
      unsigned* mcnt = base + 1024;
      if (__hip_atomic_fetch_add(mcnt, 1u, __ATOMIC_RELAXED, __HIP_MEMORY_SCOPE_AGENT) == 31u) {
        __hip_atomic_store(mcnt, 0u, __ATOMIC_RELAXED, __HIP_MEMORY_SCOPE_AGENT);
        #pragma unroll
        for (int gg = 0; gg < 32; ++gg)
          __hip_atomic_store(base + gg * 32, 0u, __ATOMIC_RELAXED, __HIP_MEMORY_SCOPE_AGENT);
        asm volatile("s_waitcnt vmcnt(0)" ::: "memory");   // resets before bcast
        #pragma unroll
        for (int gg = 0; gg < 32; ++gg)
          __hip_atomic_store(base + 2048 + gg * 32, expect, __ATOMIC_RELAXED, __HIP_MEMORY_SCOPE_AGENT);
      }
    }
    unsigned* mygen = base + 2048 + grp2 * 32;
    int guard = 0;
    while ((int)(__hip_atomic_load(mygen, __ATOMIC_RELAXED, __HIP_MEMORY_SCOPE_AGENT) - expect) < 0) {
      __builtin_amdgcn_s_sleep(8);
      if (++guard > 10000000) break;
    }
  }
  __builtin_amdgcn_s_barrier();
  // retire prefetch loads before their dest regs die (clobber hazard);
  // they've had the whole barrier wait to land -> near-free.
  asm volatile("s_waitcnt vmcnt(0)" ::: "memory");
  #pragma unroll
  for (int j = 0; j < NP; ++j)
    asm volatile("" :: "v"(pk[j]), "v"(pv[j]));
}

__device__ __forceinline__ void mac8x4(float acc[8][4], const float* wt, int k, float4 x4) {
  float4 wa = *(const float4*)(wt + k*8);
  float4 wb = *(const float4*)(wt + k*8 + 4);
  float wr[8] = {wa.x, wa.y, wa.z, wa.w, wb.x, wb.y, wb.z, wb.w};
  float xr[4] = {x4.x, x4.y, x4.z, x4.w};
  #pragma unroll
  for (int r = 0; r < 8; ++r)
    #pragma unroll
    for (int c = 0; c < 4; ++c)
      acc[r][c] += wr[r] * xr[c];
}

// cross-kslot reduce then per-wave partial to LDS
__device__ __forceinline__ void gate_reduce_store(float acc[8][4], float* red, int tid) {
  #pragma unroll
  for (int r = 0; r < 8; ++r) {
    #pragma unroll
    for (int c = 0; c < 4; ++c) {
      float v = acc[r][c];
      v += __shfl_xor(v, 16);
      v += __shfl_xor(v, 32);
      acc[r][c] = v;
    }
  }
  int wv = tid >> 6, b0 = tid & 15;
  if ((tid & 63) < 16) {
    #pragma unroll
    for (int r = 0; r < 8; ++r)
      *(float4*)(red + wv*512 + r*64 + b0*4) =
        make_float4(acc[r][0], acc[r][1], acc[r][2], acc[r][3]);
  }
}

// shared partial-merge tail: block's 16 waves -> one slice partial at bj
__device__ __forceinline__ void attn_merge_tail(float m, float S, float ca[8],
                                                float* pm, float* pS, float* pctx,
                                                SMEM* sm, int bj, int tid) {
  const int lane = tid & 63, w = tid >> 6;
  const int sub = lane & 15, grp = lane >> 4;
  #pragma unroll
  for (int off = 16; off <= 32; off <<= 1) {
    float mo = __shfl_xor(m, off);
    float So = __shfl_xor(S, off);
    float M2 = fmaxf(m, mo);
    float a0 = __expf(m - M2), a1 = __expf(mo - M2);
    S = S*a0 + So*a1;
    #pragma unroll
    for (int d = 0; d < 8; ++d)
      ca[d] = ca[d]*a0 + __shfl_xor(ca[d], off)*a1;
    m = M2;
  }
  if (lane == 0) { sm->c.wm[w] = m; sm->c.wS[w] = S; }
  if (grp == 0) {
    *(float4*)(sm->c.wctx + w*DKV + sub*8)     = make_float4(ca[0],ca[1],ca[2],ca[3]);
    *(float4*)(sm->c.wctx + w*DKV + sub*8 + 4) = make_float4(ca[4],ca[5],ca[6],ca[7]);
  }
  __syncthreads();
  if (tid < DKV) {
    int d = tid;
    float M = -1e30f;
    #pragma unroll
    for (int ww = 0; ww < 16; ++ww) M = fmaxf(M, sm->c.wm[ww]);
    float Z = 0.f, acc2 = 0.f;
    #pragma unroll
    for (int ww = 0; ww < 16; ++ww) {
      float aw = __expf(sm->c.wm[ww] - M);
      Z += aw * sm->c.wS[ww];
      acc2 += aw * sm->c.wctx[ww*DKV + d];
    }
    pctx[d*256 + bj] = acc2;
    if (d == 0) { pm[bj] = M; pS[bj] = Z; }
  }
}

// setup: initial context = mean over ALL T rows of V (fp32 source, runs once)
__device__ void attn_mean(const Params& p, float* pm, float* pS, float* pctx,
                          SMEM* sm, int bj, int tid) {
  const int lane = tid & 63, w = tid >> 6;
  const int b = bj >> 2, s = bj & 3;
  const int sub = lane & 15, grp = lane >> 4;
  const int q = 4*w + s;
  const int r0 = q*4 + grp;
  float S = 0.f;
  float ca[8] = {0.f,0.f,0.f,0.f,0.f,0.f,0.f,0.f};
  const float* vb = p.value + (size_t)b * TTS * DKV;
  #pragma unroll
  for (int j = 0; j < 8; ++j) {
    int t = r0 + 256*j;
    const float* vp = vb + (size_t)t * DKV + sub*8;
    float4 va = *(const float4*)vp;
    float4 vb4 = *(const float4*)(vp + 4);
    S += 1.f;
    ca[0]+=va.x;  ca[1]+=va.y;  ca[2]+=va.z;  ca[3]+=va.w;
    ca[4]+=vb4.x; ca[5]+=vb4.y; ca[6]+=vb4.z; ca[7]+=vb4.w;
  }
  attn_merge_tail(0.f, S, ca, pm, pS, pctx, sm, b*4 + s, tid);
}

// Phase C: attention partials, R2 mapping (slot q=4w+s, rows 4q+grp+256j),
// guarded chunk loads (lowest-FETCH form). Query row staged via coherent
// sc-loads into LDS (h2r crosses only a light barrier; its lines are
// partial-written per block so default-cached reads would see stale bytes).
template<bool BF16>
__device__ void phase_attn_main(const Params& p, const float* qrow,
                                const unsigned short* kbf, const unsigned short* vbf,
                                float* pm, float* pS, float* pctx, float* wsE,
                                SMEM* sm, int bj, int tid) {
  const int lane = tid & 63, w = tid >> 6;
  const int b = bj >> 2, s = bj & 3;
  const int len = p.enc_len[b];
  const int sub = lane & 15, grp = lane >> 4;
  const int q = 4*w + s;
  const int r0 = q*4 + grp;
  float m = -1e30f, S = 0.f;
  float ca[8] = {0.f,0.f,0.f,0.f,0.f,0.f,0.f,0.f};
  if constexpr (BF16) {
    if (tid < 32) {
      u32x4 qv;
      asm volatile("global_load_dwordx4 %0, %1, %2 sc0 sc1"
                   : "=v"(qv) : "v"((unsigned)(tid*16)), "s"(qrow + b*DKV));
      asm volatile("s_waitcnt vmcnt(0)" ::: "memory");
      *(u32x4*)&sm->c.qh2[tid*4] = qv;
    }
    __syncthreads();
  }
  int NJ = 0;
  { int d = len - 4*q; if (d > 0) { NJ = (d + 255) >> 8; if (NJ > 8) NJ = 8; } }
  if (NJ > 0) {
    float q8[8];
    if constexpr (BF16) {
      const float* qp = sm->c.qh2 + sub*8;
      float4 qa = *(const float4*)qp;
      float4 qb = *(const float4*)(qp + 4);
      q8[0]=qa.x; q8[1]=qa.y; q8[2]=qa.z; q8[3]=qa.w;
      q8[4]=qb.x; q8[5]=qb.y; q8[6]=qb.z; q8[7]=qb.w;
    } else {
      const float* qp = qrow + b*DKV + sub*8;
      float4 qa = *(const float4*)qp;
      float4 qb = *(const float4*)(qp + 4);
      q8[0]=qa.x; q8[1]=qa.y; q8[2]=qa.z; q8[3]=qa.w;
      q8[4]=qb.x; q8[5]=qb.y; q8[6]=qb.z; q8[7]=qb.w;
    }
    float e[8];
    #pragma unroll
    for (int j = 0; j < 8; ++j) e[j] = -1e30f;
    if constexpr (BF16) {
      const unsigned short* kb  = kbf + (size_t)(b*TTS)*DKV + sub*8;
      const unsigned short* vbp = vbf + (size_t)(b*TTS)*DKV + sub*8;
      uint4 kq[8], vq[8];
      #pragma unroll
      for (int j = 0; j < 8; ++j) {
        if (j < NJ) {
          int t = r0 + 256*j;
          int tc = t < len ? t : len - 1;
          kq[j] = *(const uint4*)(kb  + (size_t)tc * DKV);
          vq[j] = *(const uint4*)(vbp + (size_t)tc * DKV);
        }
      }
      #pragma unroll
      for (int j = 0; j < 8; ++j) {
        if (j < NJ) {
          float ep = blo(kq[j].x)*q8[0] + bhi(kq[j].x)*q8[1]
                   + blo(kq[j].y)*q8[2] + bhi(kq[j].y)*q8[3]
                   + blo(kq[j].z)*q8[4] + bhi(kq[j].z)*q8[5]
                   + blo(kq[j].w)*q8[6] + bhi(kq[j].w)*q8[7];
          ep += __shfl_xor(ep, 1); ep += __shfl_xor(ep, 2);
          ep += __shfl_xor(ep, 4); ep += __shfl_xor(ep, 8);
          int t = r0 + 256*j;
          e[j] = (t < len) ? ep * SCALE_F : -1e30f;
          if (b == 0 && sub == 0 && t < len) wsE[t] = e[j];
        }
      }
      m = fmaxf(fmaxf(fmaxf(e[0],e[1]), fmaxf(e[2],e[3])),
                fmaxf(fmaxf(e[4],e[5]), fmaxf(e[6],e[7])));
      float pr[8];
      #pragma unroll
      for (int j = 0; j < 8; ++j) {
        pr[j] = (e[j] > -1e29f) ? __expf(e[j] - m) : 0.f;
        S += pr[j];
      }
      #pragma unroll
      for (int j = 0; j < 8; ++j) {
        if (j < NJ) {
          ca[0] += pr[j]*blo(vq[j].x); ca[1] += pr[j]*bhi(vq[j].x);
          ca[2] += pr[j]*blo(vq[j].y); ca[3] += pr[j]*bhi(vq[j].y);
          ca[4] += pr[j]*blo(vq[j].z); ca[5] += pr[j]*bhi(vq[j].z);
          ca[6] += pr[j]*blo(vq[j].w); ca[7] += pr[j]*bhi(vq[j].w);
        }
      }
    } else {
      // fp32 fallback (small-ws path)
      for (int j = 0; j < NJ; ++j) {
        int t = r0 + 256*j;
        int tc = t < len ? t : len - 1;
        const float* kp = p.key + (size_t)(b*TTS + tc)*DKV + sub*8;
        float4 ka = *(const float4*)kp;
        float4 kb2 = *(const float4*)(kp + 4);
        float ep = ka.x*q8[0] + ka.y*q8[1] + ka.z*q8[2] + ka.w*q8[3]
                 + kb2.x*q8[4] + kb2.y*q8[5] + kb2.z*q8[6] + kb2.w*q8[7];
        ep += __shfl_xor(ep, 1); ep += __shfl_xor(ep, 2);
        ep += __shfl_xor(ep, 4); ep += __shfl_xor(ep, 8);
        e[j] = (t < len) ? ep * SCALE_F : -1e30f;
        if (b == 0 && sub == 0 && t < len) wsE[t] = e[j];
      }
      m = e[0];
      #pragma unroll
      for (int j = 1; j < 8; ++j) m = fmaxf(m, e[j]);
      float pr[8];
      #pragma unroll
      for (int j = 0; j < 8; ++j) {
        pr[j] = (e[j] > -1e29f) ? __expf(e[j] - m) : 0.f;
        S += pr[j];
      }
      for (int j = 0; j < NJ; ++j) {
        int t = r0 + 256*j;
        int tc = t < len ? t : len - 1;
        const float* vp = p.value + (size_t)(b*TTS + tc)*DKV + sub*8;
        float4 va = *(const float4*)vp;
        float4 vb4 = *(const float4*)(vp + 4);
        ca[0] += pr[j]*va.x;  ca[1] += pr[j]*va.y;
        ca[2] += pr[j]*va.z;  ca[3] += pr[j]*va.w;
        ca[4] += pr[j]*vb4.x; ca[5] += pr[j]*vb4.y;
        ca[6] += pr[j]*vb4.z; ca[7] += pr[j]*vb4.w;
      }
    }
  }
  attn_merge_tail(m, S, ca, pm, pS, pctx, sm, bj, tid);
}

template<bool BF16>
__global__ void
__attribute__((amdgpu_flat_work_group_size(NT, NT), amdgpu_waves_per_eu(4, 4)))
decoder_kernel(Params p) {
  const int tid = threadIdx.x;
  const int bj = blockIdx.x;
  float* ws = p.ws;
  unsigned* bar = (unsigned*)(ws + OFF_BAR);
  float* pm = ws + OFF_PM;
  float* pS = ws + OFF_PS;
  float* pctx = ws + OFF_PCTX;
  float* wsE = ws + OFF_WSE;
  float* embT0 = ws + OFF_EMBT;
  float* embT1 = ws + OFF_EMBT + EEM*BB;
  float* h1b0 = ws + OFF_H1;
  float* h1b1 = ws + OFF_H1 + HH1*BB;
  float* c1 = ws + OFF_C1;
  float* h2r0 = ws + OFF_H2R;
  float* h2r1 = ws + OFF_H2R + BB*DKV;
  float* h2t0 = ws + OFF_H2T;
  float* h2t1 = ws + OFF_H2T + DKV*BB;
  float* c2 = ws + OFF_C2;
  unsigned short* kbf = (unsigned short*)(ws + OFF_KBF);
  unsigned short* vbf = (unsigned short*)(ws + OFF_VBF);
  unsigned genc = 0;   // local barrier generation

  const int b_my = bj >> 2, s_my = bj & 3;
  const int len_my = p.enc_len[b_my];

  __shared__ SMEM sm;

  // -------- persistent register state: step-invariant weights & biases --------
  float wr1[8] = {0,0,0,0,0,0,0,0};
  if (tid < 896) {
    #pragma unroll
    for (int r = 0; r < 8; ++r) {
      int grow = (r >> 1)*HH1 + 2*bj + (r & 1);
      wr1[r] = (tid < 384) ? p.Wih1[(size_t)grow*384 + tid]
                           : p.Whh1[(size_t)grow*HH1 + (tid - 384)];
    }
  }
  float wr2[8] = {0,0,0,0,0,0,0,0};
  if (bj < 64 && tid < 640) {
    #pragma unroll
    for (int r = 0; r < 8; ++r) {
      int grow = (r >> 1)*DKV + 2*bj + (r & 1);
      wr2[r] = (tid < 512) ? p.Wih2[(size_t)grow*HH1 + tid]
                           : p.Whh2[(size_t)grow*DKV + (tid - 512)];
    }
  }
  float bsum1 = 0.f, bsum2 = 0.f;
  if (tid < 512) {
    int r = tid >> 6;
    int g1 = (r >> 1)*HH1 + 2*bj + (r & 1);
    bsum1 = p.bih1[g1] + p.bhh1[g1];
    if (bj < 64) {
      int g2 = (r >> 1)*DKV + 2*bj + (r & 1);
      bsum2 = p.bih2[g2] + p.bhh2[g2];
    }
  }

  // ---------------- setup ----------------
  {
    int gid = bj*NT + tid;
    for (int idx = gid; idx < (OFF_BAR - OFF_H1); idx += NB*NT) ws[OFF_H1 + idx] = 0.f;
    for (int idx = gid; idx < EEM*BB; idx += NB*NT) {
      int k = idx >> 6, b = idx & 63;
      embT0[k*64 + b] = p.emb[SOS_ID*EEM + k];
    }
    if constexpr (BF16) {
      // convert K,V fp32 -> bf16 (RNE), 8 floats -> one uint4 store
      const int NG = (BB*TTS*DKV) / 8;   // 2097152 groups per tensor
      for (int g = gid; g < NG; g += NB*NT) {
        const float4* src = (const float4*)p.key + (size_t)g*2;
        float4 a = src[0], bq = src[1];
        uint4 o;
        o.x = bfr(a.x)  | (bfr(a.y)  << 16);
        o.y = bfr(a.z)  | (bfr(a.w)  << 16);
        o.z = bfr(bq.x) | (bfr(bq.y) << 16);
        o.w = bfr(bq.z) | (bfr(bq.w) << 16);
        ((uint4*)kbf)[g] = o;
      }
      for (int g = gid; g < NG; g += NB*NT) {
        const float4* src = (const float4*)p.value + (size_t)g*2;
        float4 a = src[0], bq = src[1];
        uint4 o;
        o.x = bfr(a.x)  | (bfr(a.y)  << 16);
        o.y = bfr(a.z)  | (bfr(a.w)  << 16);
        o.z = bfr(bq.x) | (bfr(bq.y) << 16);
        o.w = bfr(bq.z) | (bfr(bq.w) << 16);
        ((uint4*)vbf)[g] = o;
      }
    }
    attn_mean(p, pm, pS, pctx, &sm, bj, tid);
  }
  gbar(bar, ++genc);   // FULL: setup writes (K/V etc.) flushed + all L2s clean

  for (int i = 0; i <= LLS; ++i) {
    const int cur = i & 1;
    float* h1c = cur ? h1b1 : h1b0;
    const float* h1p = cur ? h1b0 : h1b1;
    float* h2rc = cur ? h2r1 : h2r0;
    const float* h2rp = cur ? h2r0 : h2r1;
    float* h2tc = cur ? h2t1 : h2t0;
    const float* h2tp = cur ? h2t0 : h2t1;
    const float* et = cur ? embT1 : embT0;
    float* etn = cur ? embT0 : embT1;

    // ================= phase A =================
    // A0: combine 4 slice partials -> ctx in LDS (transposed [d][b])
    {
      int b = tid & 63, dg = tid >> 6;
      float4 m4 = *(const float4*)(pm + b*4);
      float4 s4 = *(const float4*)(pS + b*4);
      float M = fmaxf(fmaxf(m4.x, m4.y), fmaxf(m4.z, m4.w));
      float a0 = __expf(m4.x - M), a1 = __expf(m4.y - M);
      float a2 = __expf(m4.z - M), a3 = __expf(m4.w - M);
      float Z = a0*s4.x + a1*s4.y + a2*s4.z + a3*s4.w;
      float iZ = 1.f / Z;
      a0 *= iZ; a1 *= iZ; a2 *= iZ; a3 *= iZ;
      #pragma unroll
      for (int jj = 0; jj < 8; ++jj) {
        int d = dg + jj*16;
        float4 c4 = *(const float4*)(pctx + d*256 + b*4);
        sm.a.ctxT[d*64 + b] = a0*c4.x + a1*c4.y + a2*c4.z + a3*c4.w;
      }
    }
    // A1 weights: registers -> LDS (step-invariant, no global traffic)
    if (i < LLS && tid < 896) {
      *(float4*)(sm.a.u.wt + tid*8)     = make_float4(wr1[0], wr1[1], wr1[2], wr1[3]);
      *(float4*)(sm.a.u.wt + tid*8 + 4) = make_float4(wr1[4], wr1[5], wr1[6], wr1[7]);
    }
    __syncthreads();

    if (i < LLS) {
      // A1: LSTM1 for h in {2*bj, 2*bj+1}; 8 gate rows per block
      {
        const int b0 = tid & 15, ks = tid >> 4;   // 16 b-quads x 64 k-slots
        float acc[8][4];
        #pragma unroll
        for (int r = 0; r < 8; ++r) { acc[r][0]=0.f; acc[r][1]=0.f; acc[r][2]=0.f; acc[r][3]=0.f; }
        #pragma unroll
        for (int j = 0; j < 4; ++j) {             // emb segment k<256
          int k = ks*4 + j;
          float4 x4 = *(const float4*)(et + k*64 + b0*4);
          mac8x4(acc, sm.a.u.wt, k, x4);
        }
        #pragma unroll
        for (int j = 0; j < 2; ++j) {             // ctx segment
          int d = ks*2 + j;
          float4 x4 = *(const float4*)(sm.a.ctxT + d*64 + b0*4);
          mac8x4(acc, sm.a.u.wt, 256 + d, x4);
        }
        #pragma unroll
        for (int j = 0; j < 8; ++j) {             // h1 segment
          int kk = ks*8 + j;
          float4 x4 = *(const float4*)(h1p + kk*64 + b0*4);
          mac8x4(acc, sm.a.u.wt, 384 + kk, x4);
        }
        __syncthreads();    // wt reads done; red aliases wt
        gate_reduce_store(acc, sm.a.u.red, tid);
      }
      __syncthreads();
      if (tid < 512) {
        int r = tid >> 6, b = tid & 63;
        float s = 0.f;
        #pragma unroll
        for (int w2 = 0; w2 < 16; ++w2) s += sm.a.u.red[w2*512 + r*64 + b];
        s += bsum1;
        sm.a.u.red[r*64 + b] = s;
      }
      __syncthreads();
      if (tid < 128) {
        int hh = tid >> 6, b = tid & 63;
        int h = 2*bj + hh;
        float gi = sm.a.u.red[(hh+0)*64 + b];
        float gf = sm.a.u.red[(hh+2)*64 + b];
        float gg = sm.a.u.red[(hh+4)*64 + b];
        float go = sm.a.u.red[(hh+6)*64 + b];
        float co = c1[h*64 + b];
        float cn = sigm(gf)*co + sigm(gi)*tanh_f(gg);
        float hn = sigm(go)*tanh_f(cn);
        c1[h*64 + b] = cn;                     // block-private: default store
        // h1 crosses only the light A->B barrier: write-through coherent store
        asm volatile("global_store_dword %0, %1, %2 sc0 sc1"
                     :: "v"((unsigned)((h*64 + b)*4)), "v"(hn), "s"(h1c) : "memory");
      }
    }

    if (i >= 1) {
      // A2: logits for step i-1
      if (tid >= 960) {
        int ln = tid - 960;
        int oi = bj*8 + (ln >> 3);
        int sub = ln & 7;
        if (oi < BB*VVV) {
          int b = oi / VVV, v = oi - b*VVV;
          float a = 0.f;
          if (sub < 4) {
            #pragma unroll 8
            for (int e0 = 0; e0 < 32; ++e0) {
              int e = sub*32 + e0;
              a += h2rp[b*DKV + e] * p.emb[v*EEM + e];
            }
          } else {
            #pragma unroll 8
            for (int e0 = 0; e0 < 32; ++e0) {
              int d = (sub - 4)*32 + e0;
              a += sm.a.ctxT[d*64 + b] * p.emb[v*EEM + 128 + d];
            }
          }
          a += __shfl_xor(a, 1); a += __shfl_xor(a, 2); a += __shfl_xor(a, 4);
          if (sub == 0) p.out[((size_t)b*LLS + (i-1))*VVV + v] = a + p.obias[v];
        }
      }
      // A3: attention plot row i-1
      if (tid >= 896 && tid < 904) {
        int t = bj*8 + (tid - 896);
        int len0 = p.enc_len[0];
        float v = 0.f;
        if (t < len0) {
          float m0 = pm[0], m1 = pm[1], m2 = pm[2], m3 = pm[3];
          float M = fmaxf(fmaxf(m0, m1), fmaxf(m2, m3));
          float Z = __expf(m0 - M)*pS[0] + __expf(m1 - M)*pS[1]
                  + __expf(m2 - M)*pS[2] + __expf(m3 - M)*pS[3];
          v = __expf(wsE[t] - M) / Z;
        }
        p.out[PRED_SZ + (size_t)(i-1)*TTS + t] = v;
      }
    }

    if (i == LLS) break;

    // plain light A->B barrier (no prefetch here: R10 showed lines issued
    // this far ahead get evicted by the B->C prefetch + B traffic)
    gbar_light(bar, ++genc);

    // ================= phase B =================
    if (bj < 64) {
      if (tid < 640) {
        *(float4*)(sm.a.u.wt + tid*8)     = make_float4(wr2[0], wr2[1], wr2[2], wr2[3]);
        *(float4*)(sm.a.u.wt + tid*8 + 4) = make_float4(wr2[4], wr2[5], wr2[6], wr2[7]);
      }
      __syncthreads();
      {
        const int b0 = tid & 15, ks = tid >> 4;
        float acc[8][4];
        #pragma unroll
        for (int r = 0; r < 8; ++r) { acc[r][0]=0.f; acc[r][1]=0.f; acc[r][2]=0.f; acc[r][3]=0.f; }
        #pragma unroll
        for (int j = 0; j < 8; ++j) {            // h1 segment (512)
          int k = ks*8 + j;
          float4 x4 = *(const float4*)(h1c + k*64 + b0*4);
          mac8x4(acc, sm.a.u.wt, k, x4);
        }
        #pragma unroll
        for (int j = 0; j < 2; ++j) {            // h2 segment (128)
          int d = ks*2 + j;
          float4 x4 = *(const float4*)(h2tp + d*64 + b0*4);
          mac8x4(acc, sm.a.u.wt, 512 + d, x4);
        }
        __syncthreads();
        gate_reduce_store(acc, sm.a.u.red, tid);
      }
      __syncthreads();
      if (tid < 512) {
        int r = tid >> 6, b = tid & 63;
        float s = 0.f;
        #pragma unroll
        for (int w2 = 0; w2 < 16; ++w2) s += sm.a.u.red[w2*512 + r*64 + b];
        s += bsum2;
        sm.a.u.red[r*64 + b] = s;
      }
      __syncthreads();
      if (tid < 128) {
        int hh = tid >> 6, b = tid & 63;
        int d2 = 2*bj + hh;
        float gi = sm.a.u.red[(hh+0)*64 + b];
        float gf = sm.a.u.red[(hh+2)*64 + b];
        float gg = sm.a.u.red[(hh+4)*64 + b];
        float go = sm.a.u.red[(hh+6)*64 + b];
        float co = c2[d2*64 + b];
        float cn = sigm(gf)*co + sigm(gi)*tanh_f(gg);
        float hn = sigm(go)*tanh_f(cn);
        c2[d2*64 + b] = cn;                    // block-private: default
        h2tc[d2*64 + b] = hn;                  // read next step across FULL: default
        // h2r crosses only the light B->C barrier: coherent write-through
        asm volatile("global_store_dword %0, %1, %2 sc0 sc1"
                     :: "v"((unsigned)((b*DKV + d2)*4)), "v"(hn), "s"(h2rc) : "memory");
      }
    } else if (bj < 128) {
      // stage embeddings for step i+1 (read next step across the FULL barrier)
      int sn = i + 1;
      if (sn < LLS && tid < 256) {
        int idx = (bj - 64)*256 + tid;
        int k = idx >> 6, b = idx & 63;
        int id = p.y[b*LLS + sn - 1];
        etn[k*64 + b] = p.emb[(size_t)id*EEM + k];
      }
    }

    // light B->C barrier with overlapped prefetch of chunks 0..3 (3MB/XCD,
    // fits L2; immediately before use -> nothing can evict it)
    if constexpr (BF16)
      gbar_light_pf<0,3>(bar, ++genc, kbf, vbf, b_my, s_my, len_my, tid);
    else
      gbar_light(bar, ++genc);

    // ================= phase C =================
    phase_attn_main<BF16>(p, h2rc, kbf, vbf, pm, pS, pctx, wsE, &sm, bj, tid);
    gbar(bar, ++genc);   // FULL: flush pctx/pm/pS/h2t/etn + one invalidate/step
  }
}

__global__ void init_bar_kernel(unsigned* bar) {
  int i = blockIdx.x * blockDim.x + threadIdx.x;
  if (i < 4096) bar[i] = 0u;
}

extern "C" void kernel_launch(void* const* d_in, const int* in_sizes, int n_in,
                              void* d_out, int out_size, void* d_ws, size_t ws_size,
                              hipStream_t stream) {
  Params prm;
  prm.key     = (const float*)d_in[0];
  prm.value   = (const float*)d_in[1];
  prm.enc_len = (const int*)d_in[2];
  prm.y       = (const int*)d_in[3];
  prm.emb     = (const float*)d_in[4];
  prm.Wih1    = (const float*)d_in[5];
  prm.Whh1    = (const float*)d_in[6];
  prm.bih1    = (const float*)d_in[7];
  prm.bhh1    = (const float*)d_in[8];
  prm.Wih2    = (const float*)d_in[9];
  prm.Whh2    = (const float*)d_in[10];
  prm.bih2    = (const float*)d_in[11];
  prm.bhh2    = (const float*)d_in[12];
  prm.obias   = (const float*)d_in[13];
  prm.out = (float*)d_out;
  prm.ws  = (float*)d_ws;

  unsigned* bar = (unsigned*)((float*)d_ws + OFF_BAR);
  init_bar_kernel<<<16, 256, 0, stream>>>(bar);

  void* args[] = { &prm };
  if (ws_size >= WS_NEED_BYTES) {
    hipError_t e = hipLaunchCooperativeKernel((const void*)decoder_kernel<true>,
                                              dim3(NB), dim3(NT), args, 0, stream);
    if (e != hipSuccess) decoder_kernel<true><<<dim3(NB), dim3(NT), 0, stream>>>(prm);
  } else {
    hipError_t e = hipLaunchCooperativeKernel((const void*)decoder_kernel<false>,
                                              dim3(NB), dim3(NT), args, 0, stream);
    if (e != hipSuccess) decoder_kernel<false><<<dim3(NB), dim3(NT), 0, stream>>>(prm);
  }
}